// Round 4
// baseline (719.437 us; speedup 1.0000x reference)
//
#include <hip/hip_runtime.h>
#include <hip/hip_bf16.h>

#define B_ROWS   524288
#define MEL_BINS 128
#define DIM      64
#define KCODES   128

// ---------------- workspace layout (floats) ----------------
#define WS_WT 0
#define WS_N0 (WS_WT + MEL_BINS*DIM)        // 8192
#define WS_N1 (WS_N0 + KCODES)              // 8320
#define WS_T0 (WS_N1 + KCODES)              // 8448
#define WS_T1 (WS_T0 + KCODES*MEL_BINS)     // 24832
#define WS_TOT (WS_T1 + KCODES*MEL_BINS)    // 41216 floats = 164864 B

// numpy pairwise_sum (scalar path) emulation for n=64 of v[d]*v[d].
__device__ __forceinline__ float np_pairwise64_sq(const float* v) {
#pragma clang fp contract(off)
    float r0 = v[0]*v[0], r1 = v[1]*v[1], r2 = v[2]*v[2], r3 = v[3]*v[3];
    float r4 = v[4]*v[4], r5 = v[5]*v[5], r6 = v[6]*v[6], r7 = v[7]*v[7];
#pragma unroll
    for (int i = 8; i < 64; i += 8) {
        r0 += v[i+0]*v[i+0]; r1 += v[i+1]*v[i+1];
        r2 += v[i+2]*v[i+2]; r3 += v[i+3]*v[i+3];
        r4 += v[i+4]*v[i+4]; r5 += v[i+5]*v[i+5];
        r6 += v[i+6]*v[i+6]; r7 += v[i+7]*v[i+7];
    }
    return ((r0 + r1) + (r2 + r3)) + ((r4 + r5) + (r6 + r7));
}

__global__ __launch_bounds__(256) void rvq_precomp(
    const float* __restrict__ W_in, const float* __restrict__ cb0,
    const float* __restrict__ cb1, const float* __restrict__ W_out,
    float* __restrict__ ws)
{
#pragma clang fp contract(off)
    float* WT = ws + WS_WT;
    float* n0 = ws + WS_N0;
    float* n1 = ws + WS_N1;
    float* T0 = ws + WS_T0;
    float* T1 = ws + WS_T1;

    int tid = blockIdx.x * 256 + threadIdx.x;
    if (tid < 16384) {                       // T0[i][m] (mel path has loose threshold)
        int i = tid >> 7, m = tid & 127;
        double a = 0.0;
        for (int d = 0; d < DIM; ++d)
            a = fma((double)cb0[i*DIM + d], (double)W_out[m*DIM + d], a);
        T0[tid] = (float)a;
    } else if (tid < 32768) {                // T1[i][m]
        int t = tid - 16384;
        int i = t >> 7, m = t & 127;
        double a = 0.0;
        for (int d = 0; d < DIM; ++d)
            a = fma((double)cb1[i*DIM + d], (double)W_out[m*DIM + d], a);
        T1[t] = (float)a;
    } else if (tid < 40960) {                // WT[j][d] = W_in[d][j]
        int t = tid - 32768;
        int j = t >> 6, d = t & 63;
        WT[t] = W_in[d*MEL_BINS + j];
    } else if (tid < 41216) {                // n0 / n1 (exact np pairwise)
        int t = tid - 40960;
        const float* cb = (t & 128) ? cb1 : cb0;
        float*       nn = (t & 128) ? n1  : n0;
        int k = t & 127;
        nn[k] = np_pairwise64_sq(cb + k*DIM);
    }
}

// 2 rows per thread: every wave-uniform table fetch (WT rows, cb rows) feeds
// two independent FMA chains -> halves latency exposure, doubles ILP.
// Per-row FP op ORDER is identical to the verified single-row version.
__global__ __launch_bounds__(256) void rvq_main(
    const float* __restrict__ mel,
    const float* __restrict__ b_in,
    const float* __restrict__ cb0,
    const float* __restrict__ cb1,
    const float* __restrict__ b_out,
    const float* __restrict__ ws,
    float* __restrict__ out_mel,
    float* __restrict__ out_idx)
{
#pragma clang fp contract(off)
    const float* __restrict__ WT = ws + WS_WT;
    const float* __restrict__ n0 = ws + WS_N0;
    const float* __restrict__ n1 = ws + WS_N1;
    const float* __restrict__ T0 = ws + WS_T0;
    const float* __restrict__ T1 = ws + WS_T1;

    const size_t rA = 2 * (size_t)(blockIdx.x * 256 + threadIdx.x);
    const size_t rB = rA + 1;

    // ---- z = mel @ W_in^T : ascending-j fmaf chain per d, per row
    float zA[DIM], zB[DIM];
#pragma unroll
    for (int d = 0; d < DIM; ++d) { zA[d] = 0.f; zB[d] = 0.f; }

    const float4* melA = reinterpret_cast<const float4*>(mel + rA * MEL_BINS);
    const float4* melB = reinterpret_cast<const float4*>(mel + rB * MEL_BINS);
    for (int jc = 0; jc < MEL_BINS / 4; ++jc) {
        float4 a4 = melA[jc];
        float4 b4 = melB[jc];
        const float* w = WT + jc * 4 * DIM;   // wave-uniform -> scalar loads
#pragma unroll
        for (int d = 0; d < DIM; ++d) {
            zA[d] = fmaf(w[d], a4.x, zA[d]);
            zB[d] = fmaf(w[d], b4.x, zB[d]);
        }
#pragma unroll
        for (int d = 0; d < DIM; ++d) {
            zA[d] = fmaf(w[DIM + d], a4.y, zA[d]);
            zB[d] = fmaf(w[DIM + d], b4.y, zB[d]);
        }
#pragma unroll
        for (int d = 0; d < DIM; ++d) {
            zA[d] = fmaf(w[2*DIM + d], a4.z, zA[d]);
            zB[d] = fmaf(w[2*DIM + d], b4.z, zB[d]);
        }
#pragma unroll
        for (int d = 0; d < DIM; ++d) {
            zA[d] = fmaf(w[3*DIM + d], a4.w, zA[d]);
            zB[d] = fmaf(w[3*DIM + d], b4.w, zB[d]);
        }
    }
#pragma unroll
    for (int d = 0; d < DIM; ++d) { zA[d] = zA[d] + b_in[d]; zB[d] = zB[d] + b_in[d]; }

    // ================= codebook 0 =================
    float sA, sB;
    {   // np pairwise sum of squares, 8 accumulators + fixed tree, per row
        float a0 = zA[0]*zA[0], a1 = zA[1]*zA[1], a2 = zA[2]*zA[2], a3 = zA[3]*zA[3];
        float a4 = zA[4]*zA[4], a5 = zA[5]*zA[5], a6 = zA[6]*zA[6], a7 = zA[7]*zA[7];
        float b0 = zB[0]*zB[0], b1 = zB[1]*zB[1], b2 = zB[2]*zB[2], b3 = zB[3]*zB[3];
        float b4 = zB[4]*zB[4], b5 = zB[5]*zB[5], b6 = zB[6]*zB[6], b7 = zB[7]*zB[7];
#pragma unroll
        for (int i = 8; i < 64; i += 8) {
            a0 += zA[i+0]*zA[i+0]; a1 += zA[i+1]*zA[i+1];
            a2 += zA[i+2]*zA[i+2]; a3 += zA[i+3]*zA[i+3];
            a4 += zA[i+4]*zA[i+4]; a5 += zA[i+5]*zA[i+5];
            a6 += zA[i+6]*zA[i+6]; a7 += zA[i+7]*zA[i+7];
            b0 += zB[i+0]*zB[i+0]; b1 += zB[i+1]*zB[i+1];
            b2 += zB[i+2]*zB[i+2]; b3 += zB[i+3]*zB[i+3];
            b4 += zB[i+4]*zB[i+4]; b5 += zB[i+5]*zB[i+5];
            b6 += zB[i+6]*zB[i+6]; b7 += zB[i+7]*zB[i+7];
        }
        sA = ((a0 + a1) + (a2 + a3)) + ((a4 + a5) + (a6 + a7));
        sB = ((b0 + b1) + (b2 + b3)) + ((b4 + b5) + (b6 + b7));
    }

    float bestA = 3.4e38f, bestB = 3.4e38f; int i0A = 0, i0B = 0;
#pragma unroll 2
    for (int k = 0; k < KCODES; ++k) {
        const float* c = cb0 + k * DIM;       // wave-uniform -> scalar loads
        float accA = 0.f, accB = 0.f;
#pragma unroll
        for (int d = 0; d < DIM; ++d) {       // ascending d, 1 accumulator per row
            accA = fmaf(c[d], zA[d], accA);
            accB = fmaf(c[d], zB[d], accB);
        }
        float dA = (sA - 2.0f*accA) + n0[k];
        float dB = (sB - 2.0f*accB) + n0[k];
        if (dA < bestA) { bestA = dA; i0A = k; }   // strict < = first-min (np.argmin)
        if (dB < bestB) { bestB = dB; i0B = k; }
    }

    // residual: elementwise rounded sub (per-lane gathers, L1/L2-hot)
    {
        const float* cA = cb0 + (size_t)i0A * DIM;
        const float* cB = cb0 + (size_t)i0B * DIM;
#pragma unroll
        for (int d = 0; d < DIM; ++d) { zA[d] = zA[d] - cA[d]; zB[d] = zB[d] - cB[d]; }
    }

    // ================= codebook 1 =================
    {
        float a0 = zA[0]*zA[0], a1 = zA[1]*zA[1], a2 = zA[2]*zA[2], a3 = zA[3]*zA[3];
        float a4 = zA[4]*zA[4], a5 = zA[5]*zA[5], a6 = zA[6]*zA[6], a7 = zA[7]*zA[7];
        float b0 = zB[0]*zB[0], b1 = zB[1]*zB[1], b2 = zB[2]*zB[2], b3 = zB[3]*zB[3];
        float b4 = zB[4]*zB[4], b5 = zB[5]*zB[5], b6 = zB[6]*zB[6], b7 = zB[7]*zB[7];
#pragma unroll
        for (int i = 8; i < 64; i += 8) {
            a0 += zA[i+0]*zA[i+0]; a1 += zA[i+1]*zA[i+1];
            a2 += zA[i+2]*zA[i+2]; a3 += zA[i+3]*zA[i+3];
            a4 += zA[i+4]*zA[i+4]; a5 += zA[i+5]*zA[i+5];
            a6 += zA[i+6]*zA[i+6]; a7 += zA[i+7]*zA[i+7];
            b0 += zB[i+0]*zB[i+0]; b1 += zB[i+1]*zB[i+1];
            b2 += zB[i+2]*zB[i+2]; b3 += zB[i+3]*zB[i+3];
            b4 += zB[i+4]*zB[i+4]; b5 += zB[i+5]*zB[i+5];
            b6 += zB[i+6]*zB[i+6]; b7 += zB[i+7]*zB[i+7];
        }
        sA = ((a0 + a1) + (a2 + a3)) + ((a4 + a5) + (a6 + a7));
        sB = ((b0 + b1) + (b2 + b3)) + ((b4 + b5) + (b6 + b7));
    }

    bestA = 3.4e38f; bestB = 3.4e38f; int i1A = 0, i1B = 0;
#pragma unroll 2
    for (int k = 0; k < KCODES; ++k) {
        const float* c = cb1 + k * DIM;
        float accA = 0.f, accB = 0.f;
#pragma unroll
        for (int d = 0; d < DIM; ++d) {
            accA = fmaf(c[d], zA[d], accA);
            accB = fmaf(c[d], zB[d], accB);
        }
        float dA = (sA - 2.0f*accA) + n1[k];
        float dB = (sB - 2.0f*accB) + n1[k];
        if (dA < bestA) { bestA = dA; i1A = k; }
        if (dB < bestB) { bestB = dB; i1B = k; }
    }

    // ---- decode: out = T0[i0] + T1[i1] + b_out
    const float4* t0A = reinterpret_cast<const float4*>(T0 + (size_t)i0A * MEL_BINS);
    const float4* t1A = reinterpret_cast<const float4*>(T1 + (size_t)i1A * MEL_BINS);
    const float4* t0B = reinterpret_cast<const float4*>(T0 + (size_t)i0B * MEL_BINS);
    const float4* t1B = reinterpret_cast<const float4*>(T1 + (size_t)i1B * MEL_BINS);
    float4* outA = reinterpret_cast<float4*>(out_mel + rA * MEL_BINS);
    float4* outB = reinterpret_cast<float4*>(out_mel + rB * MEL_BINS);
#pragma unroll 4
    for (int q = 0; q < MEL_BINS / 4; ++q) {
        float4 p = t0A[q], r = t1A[q];
        float4 u = t0B[q], v = t1B[q];
        float bx = b_out[4*q + 0], by = b_out[4*q + 1];
        float bz = b_out[4*q + 2], bw = b_out[4*q + 3];
        float4 oA, oB;
        oA.x = p.x + r.x + bx;  oA.y = p.y + r.y + by;
        oA.z = p.z + r.z + bz;  oA.w = p.w + r.w + bw;
        oB.x = u.x + v.x + bx;  oB.y = u.y + v.y + by;
        oB.z = u.z + v.z + bz;  oB.w = u.w + v.w + bw;
        outA[q] = oA;
        outB[q] = oB;
    }

    out_idx[2*rA + 0] = (float)i0A;
    out_idx[2*rA + 1] = (float)i1A;
    out_idx[2*rB + 0] = (float)i0B;
    out_idx[2*rB + 1] = (float)i1B;
}

extern "C" void kernel_launch(void* const* d_in, const int* in_sizes, int n_in,
                              void* d_out, int out_size, void* d_ws, size_t ws_size,
                              hipStream_t stream)
{
    const float* mel   = (const float*)d_in[0];
    const float* W_in  = (const float*)d_in[1];
    const float* b_in  = (const float*)d_in[2];
    const float* cb0   = (const float*)d_in[3];
    const float* cb1   = (const float*)d_in[4];
    const float* W_out = (const float*)d_in[5];
    const float* b_out = (const float*)d_in[6];

    float* ws      = (float*)d_ws;
    float* out_mel = (float*)d_out;
    float* out_idx = (float*)d_out + (size_t)B_ROWS * MEL_BINS;

    rvq_precomp<<<(WS_TOT + 255) / 256, 256, 0, stream>>>(W_in, cb0, cb1, W_out, ws);
    rvq_main<<<B_ROWS / 512, 256, 0, stream>>>(mel, b_in, cb0, cb1, b_out, ws,
                                               out_mel, out_idx);
}

// Round 5
// 611.012 us; speedup vs baseline: 1.1775x; 1.1775x over previous
//
#include <hip/hip_runtime.h>
#include <hip/hip_bf16.h>

#define B_ROWS   524288
#define MEL_BINS 128
#define DIM      64
#define KCODES   128

// ---------------- workspace layout (floats) ----------------
#define WS_WT 0
#define WS_N0 (WS_WT + MEL_BINS*DIM)        // 8192
#define WS_N1 (WS_N0 + KCODES)              // 8320
#define WS_T0 (WS_N1 + KCODES)              // 8448
#define WS_T1 (WS_T0 + KCODES*MEL_BINS)     // 24832
#define WS_TOT (WS_T1 + KCODES*MEL_BINS)    // 41216 floats = 164864 B

// numpy pairwise_sum (scalar path) emulation for n=64 of v[d]*v[d].
__device__ __forceinline__ float np_pairwise64_sq(const float* v) {
#pragma clang fp contract(off)
    float r0 = v[0]*v[0], r1 = v[1]*v[1], r2 = v[2]*v[2], r3 = v[3]*v[3];
    float r4 = v[4]*v[4], r5 = v[5]*v[5], r6 = v[6]*v[6], r7 = v[7]*v[7];
#pragma unroll
    for (int i = 8; i < 64; i += 8) {
        r0 += v[i+0]*v[i+0]; r1 += v[i+1]*v[i+1];
        r2 += v[i+2]*v[i+2]; r3 += v[i+3]*v[i+3];
        r4 += v[i+4]*v[i+4]; r5 += v[i+5]*v[i+5];
        r6 += v[i+6]*v[i+6]; r7 += v[i+7]*v[i+7];
    }
    return ((r0 + r1) + (r2 + r3)) + ((r4 + r5) + (r6 + r7));
}

__global__ __launch_bounds__(256) void rvq_precomp(
    const float* __restrict__ W_in, const float* __restrict__ cb0,
    const float* __restrict__ cb1, const float* __restrict__ W_out,
    float* __restrict__ ws)
{
#pragma clang fp contract(off)
    float* WT = ws + WS_WT;
    float* n0 = ws + WS_N0;
    float* n1 = ws + WS_N1;
    float* T0 = ws + WS_T0;
    float* T1 = ws + WS_T1;

    int tid = blockIdx.x * 256 + threadIdx.x;
    if (tid < 16384) {                       // T0[i][m] (mel path: loose threshold)
        int i = tid >> 7, m = tid & 127;
        double a = 0.0;
        for (int d = 0; d < DIM; ++d)
            a = fma((double)cb0[i*DIM + d], (double)W_out[m*DIM + d], a);
        T0[tid] = (float)a;
    } else if (tid < 32768) {                // T1[i][m]
        int t = tid - 16384;
        int i = t >> 7, m = t & 127;
        double a = 0.0;
        for (int d = 0; d < DIM; ++d)
            a = fma((double)cb1[i*DIM + d], (double)W_out[m*DIM + d], a);
        T1[t] = (float)a;
    } else if (tid < 40960) {                // WT[j][d] = W_in[d][j]
        int t = tid - 32768;
        int j = t >> 6, d = t & 63;
        WT[t] = W_in[d*MEL_BINS + j];
    } else if (tid < 41216) {                // n0 / n1 (exact np pairwise)
        int t = tid - 40960;
        const float* cb = (t & 128) ? cb1 : cb0;
        float*       nn = (t & 128) ? n1  : n0;
        int k = t & 127;
        nn[k] = np_pairwise64_sq(cb + k*DIM);
    }
}

// 1 row/thread. __launch_bounds__(256,4): VGPR cap 128 so z[64] + working set
// live in ARCH VGPRs (no AGPR shuffling), 4 waves/SIMD for latency hiding.
// FP op order is the R3-verified np-f32 emulation — DO NOT REORDER.
__global__ __launch_bounds__(256, 4) void rvq_main(
    const float* __restrict__ mel,
    const float* __restrict__ b_in,
    const float* __restrict__ cb0,
    const float* __restrict__ cb1,
    const float* __restrict__ b_out,
    const float* __restrict__ ws,
    float* __restrict__ out_mel,
    float* __restrict__ out_idx)
{
#pragma clang fp contract(off)
    const float* __restrict__ WT = ws + WS_WT;
    const float* __restrict__ n0 = ws + WS_N0;
    const float* __restrict__ n1 = ws + WS_N1;
    const float* __restrict__ T0 = ws + WS_T0;
    const float* __restrict__ T1 = ws + WS_T1;

    const int b = blockIdx.x * 256 + threadIdx.x;

    // ---- z = mel @ W_in^T : ascending-j fmaf chain per d
    float z[DIM];
#pragma unroll
    for (int d = 0; d < DIM; ++d) z[d] = 0.f;

    const float4* melr = reinterpret_cast<const float4*>(mel + (size_t)b * MEL_BINS);
    for (int jc = 0; jc < MEL_BINS / 4; ++jc) {
        float4 m4 = melr[jc];
        const float* w = WT + jc * 4 * DIM;    // wave-uniform -> scalar loads
#pragma unroll
        for (int d = 0; d < DIM; ++d) z[d] = fmaf(w[d],         m4.x, z[d]);
#pragma unroll
        for (int d = 0; d < DIM; ++d) z[d] = fmaf(w[DIM + d],   m4.y, z[d]);
#pragma unroll
        for (int d = 0; d < DIM; ++d) z[d] = fmaf(w[2*DIM + d], m4.z, z[d]);
#pragma unroll
        for (int d = 0; d < DIM; ++d) z[d] = fmaf(w[3*DIM + d], m4.w, z[d]);
    }
#pragma unroll
    for (int d = 0; d < DIM; ++d) z[d] = z[d] + b_in[d];

    // ================= codebook 0 =================
    float s0 = z[0]*z[0], s1 = z[1]*z[1], s2 = z[2]*z[2], s3 = z[3]*z[3];
    float s4 = z[4]*z[4], s5 = z[5]*z[5], s6 = z[6]*z[6], s7 = z[7]*z[7];
#pragma unroll
    for (int i = 8; i < 64; i += 8) {
        s0 += z[i+0]*z[i+0]; s1 += z[i+1]*z[i+1];
        s2 += z[i+2]*z[i+2]; s3 += z[i+3]*z[i+3];
        s4 += z[i+4]*z[i+4]; s5 += z[i+5]*z[i+5];
        s6 += z[i+6]*z[i+6]; s7 += z[i+7]*z[i+7];
    }
    float sum_rr = ((s0 + s1) + (s2 + s3)) + ((s4 + s5) + (s6 + s7));

    float best0 = 3.4e38f; int i0 = 0;
#pragma unroll 2
    for (int k = 0; k < KCODES; ++k) {
        const float* c = cb0 + k * DIM;        // wave-uniform -> scalar loads
        float acc = 0.f;
#pragma unroll
        for (int d = 0; d < DIM; ++d) acc = fmaf(c[d], z[d], acc);  // ascending d
        float dist = (sum_rr - 2.0f*acc) + n0[k];
        if (dist < best0) { best0 = dist; i0 = k; } // strict < = first-min
    }

    // residual = r - code : elementwise rounded sub
    {
        const float* c = cb0 + (size_t)i0 * DIM;
#pragma unroll
        for (int d = 0; d < DIM; ++d) z[d] = z[d] - c[d];
    }

    // ================= codebook 1 =================
    s0 = z[0]*z[0]; s1 = z[1]*z[1]; s2 = z[2]*z[2]; s3 = z[3]*z[3];
    s4 = z[4]*z[4]; s5 = z[5]*z[5]; s6 = z[6]*z[6]; s7 = z[7]*z[7];
#pragma unroll
    for (int i = 8; i < 64; i += 8) {
        s0 += z[i+0]*z[i+0]; s1 += z[i+1]*z[i+1];
        s2 += z[i+2]*z[i+2]; s3 += z[i+3]*z[i+3];
        s4 += z[i+4]*z[i+4]; s5 += z[i+5]*z[i+5];
        s6 += z[i+6]*z[i+6]; s7 += z[i+7]*z[i+7];
    }
    sum_rr = ((s0 + s1) + (s2 + s3)) + ((s4 + s5) + (s6 + s7));

    float best1 = 3.4e38f; int i1 = 0;
#pragma unroll 2
    for (int k = 0; k < KCODES; ++k) {
        const float* c = cb1 + k * DIM;
        float acc = 0.f;
#pragma unroll
        for (int d = 0; d < DIM; ++d) acc = fmaf(c[d], z[d], acc);
        float dist = (sum_rr - 2.0f*acc) + n1[k];
        if (dist < best1) { best1 = dist; i1 = k; }
    }

    // ---- decode: out = T0[i0] + T1[i1] + b_out
    const float4* t0r = reinterpret_cast<const float4*>(T0 + (size_t)i0 * MEL_BINS);
    const float4* t1r = reinterpret_cast<const float4*>(T1 + (size_t)i1 * MEL_BINS);
    float4* outr = reinterpret_cast<float4*>(out_mel + (size_t)b * MEL_BINS);
#pragma unroll 4
    for (int q = 0; q < MEL_BINS / 4; ++q) {
        float4 a = t0r[q], c = t1r[q];
        float4 o;
        o.x = a.x + c.x + b_out[4*q + 0];
        o.y = a.y + c.y + b_out[4*q + 1];
        o.z = a.z + c.z + b_out[4*q + 2];
        o.w = a.w + c.w + b_out[4*q + 3];
        outr[q] = o;
    }

    out_idx[2*(size_t)b + 0] = (float)i0;
    out_idx[2*(size_t)b + 1] = (float)i1;
}

extern "C" void kernel_launch(void* const* d_in, const int* in_sizes, int n_in,
                              void* d_out, int out_size, void* d_ws, size_t ws_size,
                              hipStream_t stream)
{
    const float* mel   = (const float*)d_in[0];
    const float* W_in  = (const float*)d_in[1];
    const float* b_in  = (const float*)d_in[2];
    const float* cb0   = (const float*)d_in[3];
    const float* cb1   = (const float*)d_in[4];
    const float* W_out = (const float*)d_in[5];
    const float* b_out = (const float*)d_in[6];

    float* ws      = (float*)d_ws;
    float* out_mel = (float*)d_out;
    float* out_idx = (float*)d_out + (size_t)B_ROWS * MEL_BINS;

    rvq_precomp<<<(WS_TOT + 255) / 256, 256, 0, stream>>>(W_in, cb0, cb1, W_out, ws);
    rvq_main<<<B_ROWS / 256, 256, 0, stream>>>(mel, b_in, cb0, cb1, b_out, ws,
                                               out_mel, out_idx);
}

// Round 6
// 591.341 us; speedup vs baseline: 1.2166x; 1.0333x over previous
//
#include <hip/hip_runtime.h>
#include <hip/hip_bf16.h>

#define B_ROWS   524288
#define MEL_BINS 128
#define DIM      64
#define KCODES   128

// ---------------- workspace layout (floats) ----------------
#define WS_WT 0
#define WS_N0 (WS_WT + MEL_BINS*DIM)        // 8192
#define WS_N1 (WS_N0 + KCODES)              // 8320
#define WS_T0 (WS_N1 + KCODES)              // 8448
#define WS_T1 (WS_T0 + KCODES*MEL_BINS)     // 24832
#define WS_TOT (WS_T1 + KCODES*MEL_BINS)    // 41216 floats = 164864 B

// numpy pairwise_sum (scalar path) emulation for n=64 of v[d]*v[d].
__device__ __forceinline__ float np_pairwise64_sq(const float* v) {
#pragma clang fp contract(off)
    float r0 = v[0]*v[0], r1 = v[1]*v[1], r2 = v[2]*v[2], r3 = v[3]*v[3];
    float r4 = v[4]*v[4], r5 = v[5]*v[5], r6 = v[6]*v[6], r7 = v[7]*v[7];
#pragma unroll
    for (int i = 8; i < 64; i += 8) {
        r0 += v[i+0]*v[i+0]; r1 += v[i+1]*v[i+1];
        r2 += v[i+2]*v[i+2]; r3 += v[i+3]*v[i+3];
        r4 += v[i+4]*v[i+4]; r5 += v[i+5]*v[i+5];
        r6 += v[i+6]*v[i+6]; r7 += v[i+7]*v[i+7];
    }
    return ((r0 + r1) + (r2 + r3)) + ((r4 + r5) + (r6 + r7));
}

__global__ __launch_bounds__(256) void rvq_precomp(
    const float* __restrict__ W_in, const float* __restrict__ cb0,
    const float* __restrict__ cb1, const float* __restrict__ W_out,
    float* __restrict__ ws)
{
#pragma clang fp contract(off)
    float* WT = ws + WS_WT;
    float* n0 = ws + WS_N0;
    float* n1 = ws + WS_N1;
    float* T0 = ws + WS_T0;
    float* T1 = ws + WS_T1;

    int tid = blockIdx.x * 256 + threadIdx.x;
    if (tid < 16384) {                       // T0[i][m] (mel path: loose threshold)
        int i = tid >> 7, m = tid & 127;
        double a = 0.0;
        for (int d = 0; d < DIM; ++d)
            a = fma((double)cb0[i*DIM + d], (double)W_out[m*DIM + d], a);
        T0[tid] = (float)a;
    } else if (tid < 32768) {                // T1[i][m]
        int t = tid - 16384;
        int i = t >> 7, m = t & 127;
        double a = 0.0;
        for (int d = 0; d < DIM; ++d)
            a = fma((double)cb1[i*DIM + d], (double)W_out[m*DIM + d], a);
        T1[t] = (float)a;
    } else if (tid < 40960) {                // WT[j][d] = W_in[d][j]
        int t = tid - 32768;
        int j = t >> 6, d = t & 63;
        WT[t] = W_in[d*MEL_BINS + j];
    } else if (tid < 41216) {                // n0 / n1 (exact np pairwise)
        int t = tid - 40960;
        const float* cb = (t & 128) ? cb1 : cb0;
        float*       nn = (t & 128) ? n1  : n0;
        int k = t & 127;
        nn[k] = np_pairwise64_sq(cb + k*DIM);
    }
}

// 1 row/thread. amdgpu_waves_per_eu(4,4): allocator targets EXACTLY 4 waves/EU
// -> 128-reg arch budget, no AGPR offload of z[] (gfx950 unified file makes
// that offload pure loss: 2x VALU ops for zero occupancy).
// FP op order is the R3-verified np-f32 emulation — DO NOT REORDER.
__global__ __launch_bounds__(256)
__attribute__((amdgpu_waves_per_eu(4, 4)))
void rvq_main(
    const float* __restrict__ mel,
    const float* __restrict__ b_in,
    const float* __restrict__ cb0,
    const float* __restrict__ cb1,
    const float* __restrict__ b_out,
    const float* __restrict__ ws,
    float* __restrict__ out_mel,
    float* __restrict__ out_idx)
{
#pragma clang fp contract(off)
    const float* __restrict__ WT = ws + WS_WT;
    const float* __restrict__ n0 = ws + WS_N0;
    const float* __restrict__ n1 = ws + WS_N1;
    const float* __restrict__ T0 = ws + WS_T0;
    const float* __restrict__ T1 = ws + WS_T1;

    const int b = blockIdx.x * 256 + threadIdx.x;

    // ---- z = mel @ W_in^T : ascending-j fmaf chain per d
    float z[DIM];
#pragma unroll
    for (int d = 0; d < DIM; ++d) z[d] = 0.f;

    const float4* melr = reinterpret_cast<const float4*>(mel + (size_t)b * MEL_BINS);
    for (int jc = 0; jc < MEL_BINS / 4; ++jc) {
        float4 m4 = melr[jc];
        const float* w = WT + jc * 4 * DIM;    // wave-uniform -> scalar loads
#pragma unroll
        for (int d = 0; d < DIM; ++d) z[d] = fmaf(w[d],         m4.x, z[d]);
#pragma unroll
        for (int d = 0; d < DIM; ++d) z[d] = fmaf(w[DIM + d],   m4.y, z[d]);
#pragma unroll
        for (int d = 0; d < DIM; ++d) z[d] = fmaf(w[2*DIM + d], m4.z, z[d]);
#pragma unroll
        for (int d = 0; d < DIM; ++d) z[d] = fmaf(w[3*DIM + d], m4.w, z[d]);
    }
#pragma unroll
    for (int d = 0; d < DIM; ++d) z[d] = z[d] + b_in[d];

    // ================= codebook 0 =================
    float s0 = z[0]*z[0], s1 = z[1]*z[1], s2 = z[2]*z[2], s3 = z[3]*z[3];
    float s4 = z[4]*z[4], s5 = z[5]*z[5], s6 = z[6]*z[6], s7 = z[7]*z[7];
#pragma unroll
    for (int i = 8; i < 64; i += 8) {
        s0 += z[i+0]*z[i+0]; s1 += z[i+1]*z[i+1];
        s2 += z[i+2]*z[i+2]; s3 += z[i+3]*z[i+3];
        s4 += z[i+4]*z[i+4]; s5 += z[i+5]*z[i+5];
        s6 += z[i+6]*z[i+6]; s7 += z[i+7]*z[i+7];
    }
    float sum_rr = ((s0 + s1) + (s2 + s3)) + ((s4 + s5) + (s6 + s7));

    float best0 = 3.4e38f; int i0 = 0;
#pragma unroll 2
    for (int k = 0; k < KCODES; ++k) {
        const float* c = cb0 + k * DIM;        // wave-uniform -> scalar loads
        float acc = 0.f;
#pragma unroll
        for (int d = 0; d < DIM; ++d) acc = fmaf(c[d], z[d], acc);  // ascending d
        float dist = (sum_rr - 2.0f*acc) + n0[k];
        if (dist < best0) { best0 = dist; i0 = k; } // strict < = first-min
    }

    // residual = r - code : elementwise rounded sub
    {
        const float* c = cb0 + (size_t)i0 * DIM;
#pragma unroll
        for (int d = 0; d < DIM; ++d) z[d] = z[d] - c[d];
    }

    // ================= codebook 1 =================
    s0 = z[0]*z[0]; s1 = z[1]*z[1]; s2 = z[2]*z[2]; s3 = z[3]*z[3];
    s4 = z[4]*z[4]; s5 = z[5]*z[5]; s6 = z[6]*z[6]; s7 = z[7]*z[7];
#pragma unroll
    for (int i = 8; i < 64; i += 8) {
        s0 += z[i+0]*z[i+0]; s1 += z[i+1]*z[i+1];
        s2 += z[i+2]*z[i+2]; s3 += z[i+3]*z[i+3];
        s4 += z[i+4]*z[i+4]; s5 += z[i+5]*z[i+5];
        s6 += z[i+6]*z[i+6]; s7 += z[i+7]*z[i+7];
    }
    sum_rr = ((s0 + s1) + (s2 + s3)) + ((s4 + s5) + (s6 + s7));

    float best1 = 3.4e38f; int i1 = 0;
#pragma unroll 2
    for (int k = 0; k < KCODES; ++k) {
        const float* c = cb1 + k * DIM;
        float acc = 0.f;
#pragma unroll
        for (int d = 0; d < DIM; ++d) acc = fmaf(c[d], z[d], acc);
        float dist = (sum_rr - 2.0f*acc) + n1[k];
        if (dist < best1) { best1 = dist; i1 = k; }
    }

    // ---- decode: out = T0[i0] + T1[i1] + b_out
    const float4* t0r = reinterpret_cast<const float4*>(T0 + (size_t)i0 * MEL_BINS);
    const float4* t1r = reinterpret_cast<const float4*>(T1 + (size_t)i1 * MEL_BINS);
    float4* outr = reinterpret_cast<float4*>(out_mel + (size_t)b * MEL_BINS);
#pragma unroll 4
    for (int q = 0; q < MEL_BINS / 4; ++q) {
        float4 a = t0r[q], c = t1r[q];
        float4 o;
        o.x = a.x + c.x + b_out[4*q + 0];
        o.y = a.y + c.y + b_out[4*q + 1];
        o.z = a.z + c.z + b_out[4*q + 2];
        o.w = a.w + c.w + b_out[4*q + 3];
        outr[q] = o;
    }

    out_idx[2*(size_t)b + 0] = (float)i0;
    out_idx[2*(size_t)b + 1] = (float)i1;
}

extern "C" void kernel_launch(void* const* d_in, const int* in_sizes, int n_in,
                              void* d_out, int out_size, void* d_ws, size_t ws_size,
                              hipStream_t stream)
{
    const float* mel   = (const float*)d_in[0];
    const float* W_in  = (const float*)d_in[1];
    const float* b_in  = (const float*)d_in[2];
    const float* cb0   = (const float*)d_in[3];
    const float* cb1   = (const float*)d_in[4];
    const float* W_out = (const float*)d_in[5];
    const float* b_out = (const float*)d_in[6];

    float* ws      = (float*)d_ws;
    float* out_mel = (float*)d_out;
    float* out_idx = (float*)d_out + (size_t)B_ROWS * MEL_BINS;

    rvq_precomp<<<(WS_TOT + 255) / 256, 256, 0, stream>>>(W_in, cb0, cb1, W_out, ws);
    rvq_main<<<B_ROWS / 256, 256, 0, stream>>>(mel, b_in, cb0, cb1, b_out, ws,
                                               out_mel, out_idx);
}